// Round 1
// baseline (259.656 us; speedup 1.0000x reference)
//
#include <hip/hip_runtime.h>

typedef __bf16 bf16;
typedef __bf16 bf16x8 __attribute__((ext_vector_type(8)));
typedef float f32x4 __attribute__((ext_vector_type(4)));
typedef unsigned int u32x4 __attribute__((ext_vector_type(4)));

#define NB 2
#define NT 2048
#define NC 1024
#define NH 16
#define ND 64

__device__ __forceinline__ void async16(const void* g, void* l) {
  __builtin_amdgcn_global_load_lds(
      (const __attribute__((address_space(1))) void*)g,
      (__attribute__((address_space(3))) void*)l, 16, 0, 0);
}

__device__ __forceinline__ bf16x8 ld8(const bf16* p) {
  return *reinterpret_cast<const bf16x8*>(p);
}

// ---------------- fp32 -> bf16 convert (x) ----------------
__global__ __launch_bounds__(256) void cvt_bf16(const float* __restrict__ src,
                                                bf16* __restrict__ dst, int n) {
  int i = (blockIdx.x * 256 + threadIdx.x) * 8;
  if (i + 8 <= n) {
    const float4* s = (const float4*)(src + i);
    float4 a = s[0], b = s[1];
    bf16x8 o;
    o[0] = (bf16)a.x; o[1] = (bf16)a.y; o[2] = (bf16)a.z; o[3] = (bf16)a.w;
    o[4] = (bf16)b.x; o[5] = (bf16)b.y; o[6] = (bf16)b.z; o[7] = (bf16)b.w;
    *(bf16x8*)(dst + i) = o;
  }
}

// ------------- transpose + convert: src fp32 [R][Cc] -> dst bf16 [Cc][R] -------------
__global__ __launch_bounds__(256) void transpose_cvt(const float* __restrict__ src,
                                                     bf16* __restrict__ dst,
                                                     int R, int Cc) {
  __shared__ float tile[32][33];
  int tx = threadIdx.x & 31, ty = threadIdx.x >> 5;
  int r0 = blockIdx.y * 32, c0 = blockIdx.x * 32;
#pragma unroll
  for (int i = 0; i < 4; ++i)
    tile[ty + i * 8][tx] = src[(size_t)(r0 + ty + i * 8) * Cc + c0 + tx];
  __syncthreads();
#pragma unroll
  for (int i = 0; i < 4; ++i)
    dst[(size_t)(c0 + ty + i * 8) * R + r0 + tx] = (bf16)tile[tx][ty + i * 8];
}

// ---------------- QKV GEMM: [4096,1024] x [3072,1024]^T, scatter to Q/K/V [B,H,T,D] ----------------
__global__ __launch_bounds__(256, 2) void gemm_qkv(
    const bf16* __restrict__ A,    // [4096][1024]
    const bf16* __restrict__ Bt,   // [3072][1024]  (W_attn^T)
    const float* __restrict__ bias,// [3072]
    bf16* __restrict__ Qo, bf16* __restrict__ Ko, bf16* __restrict__ Vo) {
  const int K = 1024;
  __shared__ bf16 As[128 * 32];
  __shared__ bf16 Bs[128 * 32];
  const int tid = threadIdx.x;
  const int lane = tid & 63, wv = tid >> 6;
  const int quad = lane >> 4, ln = lane & 15;
  const int m0 = blockIdx.x * 128, n0 = blockIdx.y * 128;
  const int wr = (wv >> 1) * 64, wc = (wv & 1) * 64;
  const int rA = tid >> 2, cA = (tid & 3) * 8;
  f32x4 acc[4][4] = {};

  for (int kt = 0; kt < K / 32; ++kt) {
    const int k0 = kt * 32;
#pragma unroll
    for (int inst = 0; inst < 2; ++inst) {
      async16(A + (size_t)(m0 + inst * 64 + rA) * K + k0 + cA,
              &As[inst * 2048 + wv * 512]);
      async16(Bt + (size_t)(n0 + inst * 64 + rA) * K + k0 + cA,
              &Bs[inst * 2048 + wv * 512]);
    }
    __syncthreads();
    bf16x8 aF[4], bF[4];
#pragma unroll
    for (int i = 0; i < 4; ++i) {
      aF[i] = ld8(&As[(wr + i * 16 + ln) * 32 + quad * 8]);
      bF[i] = ld8(&Bs[(wc + i * 16 + ln) * 32 + quad * 8]);
    }
#pragma unroll
    for (int rb = 0; rb < 4; ++rb)
#pragma unroll
      for (int cb = 0; cb < 4; ++cb)
        acc[rb][cb] = __builtin_amdgcn_mfma_f32_16x16x32_bf16(
            aF[rb], bF[cb], acc[rb][cb], 0, 0, 0);
    __syncthreads();
  }
  // epilogue: scatter to q/k/v [B,H,T,D]; fold softmax scale 1/8 into Q
#pragma unroll
  for (int rb = 0; rb < 4; ++rb) {
#pragma unroll
    for (int cb = 0; cb < 4; ++cb) {
      int gn = n0 + wc + cb * 16 + ln;
      int part = gn >> 10, c = gn & 1023;
      int h = c >> 6, dd = c & 63;
      float bs = bias[gn];
      bf16* dst = part == 0 ? Qo : (part == 1 ? Ko : Vo);
      float sc = part == 0 ? 0.125f : 1.0f;
#pragma unroll
      for (int r = 0; r < 4; ++r) {
        int gm = m0 + wr + rb * 16 + quad * 4 + r;
        int b = gm >> 11, t = gm & 2047;
        dst[((size_t)(b * NH + h) * NT + t) * ND + dd] =
            (bf16)((acc[rb][cb][r] + bs) * sc);
      }
    }
  }
}

// ---------------- flash attention: per (b,h,q-tile of 128), k-tiles of 64 ----------------
__global__ __launch_bounds__(256, 2) void flash_attn_kernel(
    const bf16* __restrict__ Qg, const bf16* __restrict__ Kg,
    const bf16* __restrict__ Vg, bf16* __restrict__ Yg) {
  constexpr int LDP = 72;  // padded row length (+8 elts = +16B keeps alignment, kills conflicts)
  __shared__ bf16 Qs[128 * LDP];
  __shared__ bf16 Ks[64 * LDP];
  __shared__ bf16 Vts[64 * LDP];  // V transposed: [d][key]
  __shared__ bf16 Ps[128 * LDP];
  const int tid = threadIdx.x;
  const int lane = tid & 63, wv = tid >> 6;
  const int quad = lane >> 4, ln = lane & 15;
  const int bh = blockIdx.y;
  const int bb = bh >> 4, hh = bh & 15;
  const int qt = (int)gridDim.x - 1 - (int)blockIdx.x;  // heavy q-tiles dispatched first
  const int q0 = qt * 128;
  const bf16* Qp = Qg + ((size_t)bh * NT + q0) * ND;
  const bf16* Kbase = Kg + (size_t)bh * NT * ND;
  const bf16* Vbase = Vg + (size_t)bh * NT * ND;

  {  // stage Q tile 128x64
    int r = tid >> 1, c0 = (tid & 1) * 32;
    const u32x4* src = (const u32x4*)(Qp + r * ND + c0);
    u32x4* dst = (u32x4*)(&Qs[r * LDP + c0]);
    dst[0] = src[0]; dst[1] = src[1]; dst[2] = src[2]; dst[3] = src[3];
  }
  __syncthreads();
  bf16x8 qf[2][2];
#pragma unroll
  for (int rb = 0; rb < 2; ++rb)
#pragma unroll
    for (int ks = 0; ks < 2; ++ks)
      qf[rb][ks] = ld8(&Qs[(wv * 32 + rb * 16 + ln) * LDP + ks * 32 + quad * 8]);

  f32x4 oacc[2][4] = {};
  float mi[2][4], li[2][4];
#pragma unroll
  for (int rb = 0; rb < 2; ++rb)
#pragma unroll
    for (int r = 0; r < 4; ++r) { mi[rb][r] = -1e30f; li[rb][r] = 0.f; }

  const int ktiles = q0 / 64 + 2;
  for (int kt = 0; kt < ktiles; ++kt) {
    const int k0 = kt * 64;
    __syncthreads();  // previous iteration's readers done before restaging
    {  // stage K tile 64x64
      int r = tid >> 2, c0 = (tid & 3) * 16;
      const u32x4* src = (const u32x4*)(Kbase + (size_t)(k0 + r) * ND + c0);
      u32x4* dst = (u32x4*)(&Ks[r * LDP + c0]);
      dst[0] = src[0]; dst[1] = src[1];
    }
    {  // stage V transposed
      int r = tid >> 2, c0 = (tid & 3) * 16;
      alignas(16) bf16 tmp[16];
      const u32x4* src = (const u32x4*)(Vbase + (size_t)(k0 + r) * ND + c0);
      *(u32x4*)&tmp[0] = src[0];
      *(u32x4*)&tmp[8] = src[1];
#pragma unroll
      for (int j = 0; j < 16; ++j) Vts[(c0 + j) * LDP + r] = tmp[j];
    }
    __syncthreads();

    // S = Q K^T  (32 q-rows x 64 keys per wave)
    f32x4 sacc[2][4] = {};
    {
      bf16x8 kf[4][2];
#pragma unroll
      for (int cb = 0; cb < 4; ++cb)
#pragma unroll
        for (int ks = 0; ks < 2; ++ks)
          kf[cb][ks] = ld8(&Ks[(cb * 16 + ln) * LDP + ks * 32 + quad * 8]);
#pragma unroll
      for (int rb = 0; rb < 2; ++rb)
#pragma unroll
        for (int cb = 0; cb < 4; ++cb)
#pragma unroll
          for (int ks = 0; ks < 2; ++ks)
            sacc[rb][cb] = __builtin_amdgcn_mfma_f32_16x16x32_bf16(
                qf[rb][ks], kf[cb][ks], sacc[rb][cb], 0, 0, 0);
    }
    if (k0 + 63 > q0 + wv * 32) {  // causal mask only on diagonal-crossing tiles
#pragma unroll
      for (int rb = 0; rb < 2; ++rb)
#pragma unroll
        for (int cb = 0; cb < 4; ++cb) {
          int kc = k0 + cb * 16 + ln;
#pragma unroll
          for (int r = 0; r < 4; ++r) {
            int qr = q0 + wv * 32 + rb * 16 + quad * 4 + r;
            if (kc > qr) sacc[rb][cb][r] = -1e30f;
          }
        }
    }
    // online softmax (row stats via shfl-xor across the 16-lane quad group)
    float alpha[2][4], rs[2][4];
#pragma unroll
    for (int rb = 0; rb < 2; ++rb)
#pragma unroll
      for (int r = 0; r < 4; ++r) {
        float mx = fmaxf(fmaxf(sacc[rb][0][r], sacc[rb][1][r]),
                         fmaxf(sacc[rb][2][r], sacc[rb][3][r]));
        mx = fmaxf(mx, __shfl_xor(mx, 1));
        mx = fmaxf(mx, __shfl_xor(mx, 2));
        mx = fmaxf(mx, __shfl_xor(mx, 4));
        mx = fmaxf(mx, __shfl_xor(mx, 8));
        float mnew = fmaxf(mi[rb][r], mx);
        alpha[rb][r] = __expf(mi[rb][r] - mnew);
        mi[rb][r] = mnew;
        rs[rb][r] = 0.f;
      }
#pragma unroll
    for (int rb = 0; rb < 2; ++rb)
#pragma unroll
      for (int cb = 0; cb < 4; ++cb)
#pragma unroll
        for (int r = 0; r < 4; ++r) {
          float p = __expf(sacc[rb][cb][r] - mi[rb][r]);
          rs[rb][r] += p;
          Ps[(wv * 32 + rb * 16 + quad * 4 + r) * LDP + cb * 16 + ln] = (bf16)p;
        }
#pragma unroll
    for (int rb = 0; rb < 2; ++rb)
#pragma unroll
      for (int r = 0; r < 4; ++r) {
        float t = rs[rb][r];
        t += __shfl_xor(t, 1);
        t += __shfl_xor(t, 2);
        t += __shfl_xor(t, 4);
        t += __shfl_xor(t, 8);
        li[rb][r] = li[rb][r] * alpha[rb][r] + t;
      }
#pragma unroll
    for (int rb = 0; rb < 2; ++rb)
#pragma unroll
      for (int db = 0; db < 4; ++db)
#pragma unroll
        for (int r = 0; r < 4; ++r) oacc[rb][db][r] *= alpha[rb][r];

    // O += P V   (P re-read from LDS in A-layout; within-wave dep, waitcnt handles it)
    bf16x8 vf[4][2], pf[2][2];
#pragma unroll
    for (int db = 0; db < 4; ++db)
#pragma unroll
      for (int ks = 0; ks < 2; ++ks)
        vf[db][ks] = ld8(&Vts[(db * 16 + ln) * LDP + ks * 32 + quad * 8]);
#pragma unroll
    for (int rb = 0; rb < 2; ++rb)
#pragma unroll
      for (int ks = 0; ks < 2; ++ks)
        pf[rb][ks] = ld8(&Ps[(wv * 32 + rb * 16 + ln) * LDP + ks * 32 + quad * 8]);
#pragma unroll
    for (int rb = 0; rb < 2; ++rb)
#pragma unroll
      for (int db = 0; db < 4; ++db)
#pragma unroll
        for (int ks = 0; ks < 2; ++ks)
          oacc[rb][db] = __builtin_amdgcn_mfma_f32_16x16x32_bf16(
              pf[rb][ks], vf[db][ks], oacc[rb][db], 0, 0, 0);
  }
  // epilogue: O /= l, write y[B*T][C] at col h*64+d
#pragma unroll
  for (int rb = 0; rb < 2; ++rb)
#pragma unroll
    for (int db = 0; db < 4; ++db) {
      int col = hh * 64 + db * 16 + ln;
#pragma unroll
      for (int r = 0; r < 4; ++r) {
        int row = q0 + wv * 32 + rb * 16 + quad * 4 + r;
        Yg[((size_t)(bb * NT + row)) * NC + col] =
            (bf16)(oacc[rb][db][r] / li[rb][r]);
      }
    }
}

// ---------------- proj GEMM: [4096,1024] x [1024,1024]^T -> fp32 out ----------------
__global__ __launch_bounds__(256, 2) void gemm_proj(
    const bf16* __restrict__ A,    // [4096][1024]  (y)
    const bf16* __restrict__ Bt,   // [1024][1024]  (W_proj^T)
    const float* __restrict__ bias,// [1024]
    float* __restrict__ out) {     // [4096][1024]
  const int K = 1024;
  __shared__ bf16 As[128 * 32];
  __shared__ bf16 Bs[128 * 32];
  const int tid = threadIdx.x;
  const int lane = tid & 63, wv = tid >> 6;
  const int quad = lane >> 4, ln = lane & 15;
  const int m0 = blockIdx.x * 128, n0 = blockIdx.y * 128;
  const int wr = (wv >> 1) * 64, wc = (wv & 1) * 64;
  const int rA = tid >> 2, cA = (tid & 3) * 8;
  f32x4 acc[4][4] = {};

  for (int kt = 0; kt < K / 32; ++kt) {
    const int k0 = kt * 32;
#pragma unroll
    for (int inst = 0; inst < 2; ++inst) {
      async16(A + (size_t)(m0 + inst * 64 + rA) * K + k0 + cA,
              &As[inst * 2048 + wv * 512]);
      async16(Bt + (size_t)(n0 + inst * 64 + rA) * K + k0 + cA,
              &Bs[inst * 2048 + wv * 512]);
    }
    __syncthreads();
    bf16x8 aF[4], bF[4];
#pragma unroll
    for (int i = 0; i < 4; ++i) {
      aF[i] = ld8(&As[(wr + i * 16 + ln) * 32 + quad * 8]);
      bF[i] = ld8(&Bs[(wc + i * 16 + ln) * 32 + quad * 8]);
    }
#pragma unroll
    for (int rb = 0; rb < 4; ++rb)
#pragma unroll
      for (int cb = 0; cb < 4; ++cb)
        acc[rb][cb] = __builtin_amdgcn_mfma_f32_16x16x32_bf16(
            aF[rb], bF[cb], acc[rb][cb], 0, 0, 0);
    __syncthreads();
  }
#pragma unroll
  for (int rb = 0; rb < 4; ++rb) {
#pragma unroll
    for (int cb = 0; cb < 4; ++cb) {
      int gn = n0 + wc + cb * 16 + ln;
      float bs = bias[gn];
#pragma unroll
      for (int r = 0; r < 4; ++r) {
        int gm = m0 + wr + rb * 16 + quad * 4 + r;
        out[(size_t)gm * 1024 + gn] = acc[rb][cb][r] + bs;
      }
    }
  }
}

extern "C" void kernel_launch(void* const* d_in, const int* in_sizes, int n_in,
                              void* d_out, int out_size, void* d_ws, size_t ws_size,
                              hipStream_t stream) {
  const float* x      = (const float*)d_in[0];
  const float* W_attn = (const float*)d_in[1];
  const float* b_attn = (const float*)d_in[2];
  const float* W_proj = (const float*)d_in[3];
  const float* b_proj = (const float*)d_in[4];
  float* out = (float*)d_out;

  bf16* ws  = (bf16*)d_ws;
  bf16* xb  = ws;                          // 4096*1024 (reused as Yb after gemm_qkv)
  bf16* Wab = xb + (size_t)4096 * 1024;    // 3072*1024
  bf16* Wpb = Wab + (size_t)3072 * 1024;   // 1024*1024
  bf16* Qb  = Wpb + (size_t)1024 * 1024;   // 32*2048*64
  bf16* Kb  = Qb + (size_t)32 * 2048 * 64;
  bf16* Vb  = Kb + (size_t)32 * 2048 * 64;
  bf16* Yb  = xb;                          // alias: xb dead after gemm_qkv

  cvt_bf16<<<2048, 256, 0, stream>>>(x, xb, 4096 * 1024);
  transpose_cvt<<<dim3(96, 32), 256, 0, stream>>>(W_attn, Wab, 1024, 3072);
  transpose_cvt<<<dim3(32, 32), 256, 0, stream>>>(W_proj, Wpb, 1024, 1024);
  gemm_qkv<<<dim3(32, 24), 256, 0, stream>>>(xb, Wab, b_attn, Qb, Kb, Vb);
  flash_attn_kernel<<<dim3(16, 32), 256, 0, stream>>>(Qb, Kb, Vb, Yb);
  gemm_proj<<<dim3(32, 8), 256, 0, stream>>>(Yb, Wpb, b_proj, out);
}